// Round 6
// baseline (404.116 us; speedup 1.0000x reference)
//
#include <hip/hip_runtime.h>

#define NSRC 50000
#define NDST 10000
#define NEDGE 250000
#define NREL 4
#define NEG_SLOPE 0.2f

typedef unsigned short u16;
typedef __attribute__((ext_vector_type(8))) short bf16x8;
typedef __attribute__((ext_vector_type(4))) float f32x4;

#define GLD16(g, l) __builtin_amdgcn_global_load_lds( \
    (__attribute__((address_space(1))) void*)(void*)(g), \
    (__attribute__((address_space(3))) void*)(l), 16, 0, 0)

static __device__ __forceinline__ u16 f2b(float f) {
  unsigned u = __float_as_uint(f);
  unsigned r = (u + 0x7FFFu + ((u >> 16) & 1u)) >> 16;
  return (u16)r;
}
static __device__ __forceinline__ float b2f(u16 b) {
  return __uint_as_float((unsigned)b << 16);
}
static __device__ __forceinline__ float leaky(float x) {
  return x > 0.f ? x : NEG_SLOPE * x;
}

// ---------------- conversions ----------------
__global__ __launch_bounds__(256) void cvtx_k(const float* __restrict__ x,
                                              u16* __restrict__ xb) {
  int i = blockIdx.x * 256 + threadIdx.x;  // group of 4 elements
  float4 v = ((const float4*)x)[i];
  uint2 o;
  o.x = (unsigned)f2b(v.x) | ((unsigned)f2b(v.y) << 16);
  o.y = (unsigned)f2b(v.z) | ((unsigned)f2b(v.w) << 16);
  ((uint2*)xb)[i] = o;
}

// WB[h][n'][k'] (bf16, n-major): n'<64 -> 0.25*W[k'>>8][k'&255][h*64+n'], else 0.
// Shape [4][128][1024].
__global__ __launch_bounds__(256) void cvtwB_k(const float* __restrict__ W,
                                               u16* __restrict__ WB) {
  int g = blockIdx.x * 256 + threadIdx.x;  // 0..524287
  int h = g >> 17, rem = g & 131071;
  int np = rem >> 10, kp = rem & 1023;
  int r = kp >> 8, kk = kp & 255;
  float v = (np < 64) ? 0.25f * W[(size_t)r * 65536 + (size_t)kk * 256 + h * 64 + np]
                      : 0.f;
  WB[g] = f2b(v);
}

// WL[n][k] = loop_w[k][n] (bf16, n-major [256][256])
__global__ __launch_bounds__(256) void cvtwL_k(const float* __restrict__ loop_w,
                                               u16* __restrict__ WL) {
  int g = blockIdx.x * 256 + threadIdx.x;  // 0..65535
  int n = g >> 8, k = g & 255;
  WL[g] = f2b(loop_w[(size_t)k * 256 + n]);
}

// WAt[c][k] (bf16, n-major, 128 rows; rows>=32 zero):
//   c<16 : el weights  W[r]@attn_l[r]  (r=c>>2, h=c&3); 16-31: er weights
__global__ __launch_bounds__(256) void wa_k(const float* __restrict__ W,
                                            const float* __restrict__ al,
                                            const float* __restrict__ ar,
                                            u16* __restrict__ WAt) {
  int g = blockIdx.x * 256 + threadIdx.x;  // 0..32767
  int c = g >> 8, k = g & 255;
  float acc = 0.f;
  if (c < 32) {
    int cc = c & 15;
    int r = cc >> 2, h = cc & 3;
    const float* vec = ((c < 16) ? al : ar) + r * 256 + h * 64;
    const float* wrow = W + (size_t)r * 65536 + (size_t)k * 256 + h * 64;
    #pragma unroll 8
    for (int j = 0; j < 64; ++j) acc += wrow[j] * vec[j];
  }
  WAt[(size_t)c * 256 + k] = f2b(acc);
}

// ---------------- GEMM template ----------------
// C = A[M,KN](bf16) @ B^T where B is n-major [*][KN].
// MODE 0: f32 out, only cols<32 -> outF[row*32+col]              (elr)
// MODE 1: f32 out, all 256 cols -> outF[row*256+col]             (Cloop)
// MODE 2: f32 out, cols<64 -> outF[row*256 + hsel*64 + col]      (Cagg, per head)
template <int MODE, int KN>
__global__ __launch_bounds__(256) void gemmN_k(const u16* __restrict__ A,
                                               const u16* __restrict__ B,
                                               int M,
                                               float* __restrict__ outF,
                                               int hsel) {
  __shared__ u16 As[128 * 64];
  __shared__ u16 Bs[128 * 64];
  const int tid = threadIdx.x;
  const int w = tid >> 6, l = tid & 63;
  const int bm = blockIdx.y * 128, bn = blockIdx.x * 128;
  const int wm = (w >> 1) * 64, wn = (w & 1) * 64;
  f32x4 acc[4][4] = {};
  const int lrow = l >> 3, lchunk = l & 7;

  for (int t = 0; t < KN / 64; ++t) {
    const int k0 = t * 64;
    #pragma unroll
    for (int c = 0; c < 4; ++c) {
      int rb = (w * 4 + c) * 8;
      int row_in = rb + lrow;
      int colb = (lchunk * 16) ^ ((row_in & 7) << 4);
      long arow = bm + row_in;
      if (arow >= M) arow = M - 1;
      const char* ga = (const char*)A + ((size_t)arow * KN + k0) * 2 + colb;
      GLD16(ga, (char*)As + rb * 128);
      const char* gb = (const char*)B + ((size_t)(bn + row_in) * KN + k0) * 2 + colb;
      GLD16(gb, (char*)Bs + rb * 128);
    }
    __syncthreads();
    #pragma unroll
    for (int kk = 0; kk < 2; ++kk) {
      bf16x8 af[4], bg[4];
      #pragma unroll
      for (int m = 0; m < 4; ++m) {
        int row = wm + m * 16 + (l & 15);
        int colb = (kk * 64 + ((l >> 4) * 16)) ^ ((row & 7) << 4);
        af[m] = *(const bf16x8*)((const char*)As + row * 128 + colb);
      }
      #pragma unroll
      for (int n = 0; n < 4; ++n) {
        int row = wn + n * 16 + (l & 15);
        int colb = (kk * 64 + ((l >> 4) * 16)) ^ ((row & 7) << 4);
        bg[n] = *(const bf16x8*)((const char*)Bs + row * 128 + colb);
      }
      #pragma unroll
      for (int m = 0; m < 4; ++m)
        #pragma unroll
        for (int n = 0; n < 4; ++n)
          acc[m][n] = __builtin_amdgcn_mfma_f32_16x16x32_bf16(af[m], bg[n], acc[m][n], 0, 0, 0);
    }
    __syncthreads();
  }
  #pragma unroll
  for (int m = 0; m < 4; ++m) {
    #pragma unroll
    for (int j = 0; j < 4; ++j) {
      int row = bm + wm + m * 16 + (l >> 4) * 4 + j;
      if (row < M) {
        #pragma unroll
        for (int n = 0; n < 4; ++n) {
          int col = bn + wn + n * 16 + (l & 15);
          float v = acc[m][n][j];
          if (MODE == 0) {
            if (col < 32) outF[(size_t)row * 32 + col] = v;
          } else if (MODE == 1) {
            outF[(size_t)row * 256 + col] = v;
          } else {
            if (col < 64) outF[(size_t)row * 256 + hsel * 64 + col] = v;
          }
        }
      }
    }
  }
}

// ---------------- CSR build (all 4 relations at once) ----------------
__global__ void hist_k(const int* __restrict__ edst, int* __restrict__ counts) {
  int g = blockIdx.x * 256 + threadIdx.x;
  if (g >= NREL * NEDGE) return;
  int r = g / NEDGE;
  atomicAdd(&counts[r * NDST + edst[g]], 1);
}

__global__ __launch_bounds__(1024) void scanA_k(const int* __restrict__ counts,
                                                int* __restrict__ offsets,
                                                int* __restrict__ btot) {
  __shared__ int wsum[16];
  int tid = threadIdx.x, lane = tid & 63, wid = tid >> 6;
  int i = blockIdx.x * 1024 + tid;
  int v = (i < NREL * NDST) ? counts[i] : 0;
  int x = v;
  #pragma unroll
  for (int off = 1; off < 64; off <<= 1) {
    int t = __shfl_up(x, off);
    if (lane >= off) x += t;
  }
  if (lane == 63) wsum[wid] = x;
  __syncthreads();
  if (wid == 0) {
    int t = (lane < 16) ? wsum[lane] : 0;
    #pragma unroll
    for (int off = 1; off < 16; off <<= 1) {
      int u = __shfl_up(t, off);
      if (lane >= off) t += u;
    }
    if (lane < 16) wsum[lane] = t;
  }
  __syncthreads();
  int wpre = (wid > 0) ? wsum[wid - 1] : 0;
  int incl = x + wpre;
  if (i < NREL * NDST) offsets[i] = incl - v;
  if (tid == 1023) btot[blockIdx.x] = incl;
}

__global__ void scanB_k(const int* __restrict__ btot, int* __restrict__ carry) {
  int lane = threadIdx.x;  // 64 threads = 1 wave
  int v = (lane < 40) ? btot[lane] : 0;
  int x = v;
  #pragma unroll
  for (int off = 1; off < 64; off <<= 1) {
    int t = __shfl_up(x, off);
    if (lane >= off) x += t;
  }
  if (lane < 40) carry[lane] = x - v;
}

__global__ __launch_bounds__(1024) void scanC_k(int* __restrict__ offsets,
                                                const int* __restrict__ carry,
                                                int* __restrict__ cursor) {
  int i = blockIdx.x * 1024 + threadIdx.x;
  if (i < NREL * NDST) {
    int o = offsets[i] + carry[blockIdx.x];
    offsets[i] = o;
    cursor[i] = o;
  }
  if (i == 0) offsets[NREL * NDST] = NREL * NEDGE;
}

__global__ void scatter_k(const int* __restrict__ esrc, const int* __restrict__ edst,
                          int* __restrict__ cursor, int* __restrict__ perm_src) {
  int g = blockIdx.x * 256 + threadIdx.x;
  if (g >= NREL * NEDGE) return;
  int r = g / NEDGE;
  int pos = atomicAdd(&cursor[r * NDST + edst[g]], 1);
  perm_src[pos] = esrc[g];
}

// ---------------- fused softmax + PER-HEAD x-aggregation ----------------
// Block = one dst (512 threads, 8 waves). Wave w: relation r=w&3, pair p=w>>2.
// Softmax without max-subtraction (|e| small, exp safe in f32, shift-invariant).
// Phase B: half-wave (32 lanes x 16B) per edge, stride 4, 2-edge unroll;
// each lane holds 8 channels x 4 HEAD accumulators (alpha is per-head!).
// Writes xaggB[h][d][r*256+ch] (bf16).
__global__ __launch_bounds__(512) void agg_k(const u16* __restrict__ xb,
                                             const int* __restrict__ offs,
                                             const int* __restrict__ perm,
                                             const float* __restrict__ elr,
                                             u16* __restrict__ xaggB) {
  __shared__ float sacc[8][4][256];   // [wave][head][ch]
  __shared__ float ssum[8][4];
  const int d = blockIdx.x;
  const int tid = threadIdx.x;
  const int w = tid >> 6, lane = tid & 63;
  const int r = w & 3, p = w >> 2;
  const int seg = r * NDST + d;
  const int beg = offs[seg], end = offs[seg + 1];
  const float4 r4 = *(const float4*)(elr + (size_t)d * 32 + 16 + r * 4);

  // phase A: denom_h = sum over edges of exp(leaky(el_h + er_h))
  float s0 = 0.f, s1 = 0.f, s2 = 0.f, s3 = 0.f;
  for (int i = beg + p * 64 + lane; i < end; i += 128) {
    int s = perm[i];
    float4 l4 = *(const float4*)(elr + (size_t)s * 32 + r * 4);
    s0 += __expf(leaky(l4.x + r4.x));
    s1 += __expf(leaky(l4.y + r4.y));
    s2 += __expf(leaky(l4.z + r4.z));
    s3 += __expf(leaky(l4.w + r4.w));
  }
  #pragma unroll
  for (int off = 1; off < 64; off <<= 1) {
    s0 += __shfl_xor(s0, off);
    s1 += __shfl_xor(s1, off);
    s2 += __shfl_xor(s2, off);
    s3 += __shfl_xor(s3, off);
  }
  if (lane == 0) {
    ssum[w][0] = s0; ssum[w][1] = s1; ssum[w][2] = s2; ssum[w][3] = s3;
  }
  __syncthreads();

  // phase B
  const int lane32 = lane & 31;
  const int hw = p * 2 + (lane >> 5);
  const float rd0 = 1.f / fmaxf(ssum[r][0] + ssum[r + 4][0], 1e-9f);
  const float rd1 = 1.f / fmaxf(ssum[r][1] + ssum[r + 4][1], 1e-9f);
  const float rd2 = 1.f / fmaxf(ssum[r][2] + ssum[r + 4][2], 1e-9f);
  const float rd3 = 1.f / fmaxf(ssum[r][3] + ssum[r + 4][3], 1e-9f);
  const size_t hoff = (size_t)lane32 * 8;
  float ac[4][8];
  #pragma unroll
  for (int h = 0; h < 4; ++h)
    #pragma unroll
    for (int c = 0; c < 8; ++c) ac[h][c] = 0.f;

  int i = beg + hw;
  for (; i + 4 < end; i += 8) {
    int sA = perm[i];
    int sB = perm[i + 4];
    float4 lA = *(const float4*)(elr + (size_t)sA * 32 + r * 4);
    float4 lB = *(const float4*)(elr + (size_t)sB * 32 + r * 4);
    uint4 hA = *(const uint4*)(xb + (size_t)sA * 256 + hoff);
    uint4 hB = *(const uint4*)(xb + (size_t)sB * 256 + hoff);
    float aA[4], aB[4];
    aA[0] = __expf(leaky(lA.x + r4.x)) * rd0;
    aA[1] = __expf(leaky(lA.y + r4.y)) * rd1;
    aA[2] = __expf(leaky(lA.z + r4.z)) * rd2;
    aA[3] = __expf(leaky(lA.w + r4.w)) * rd3;
    aB[0] = __expf(leaky(lB.x + r4.x)) * rd0;
    aB[1] = __expf(leaky(lB.y + r4.y)) * rd1;
    aB[2] = __expf(leaky(lB.z + r4.z)) * rd2;
    aB[3] = __expf(leaky(lB.w + r4.w)) * rd3;
    float xA[8], xB[8];
    xA[0] = b2f((u16)(hA.x & 0xffff)); xA[1] = b2f((u16)(hA.x >> 16));
    xA[2] = b2f((u16)(hA.y & 0xffff)); xA[3] = b2f((u16)(hA.y >> 16));
    xA[4] = b2f((u16)(hA.z & 0xffff)); xA[5] = b2f((u16)(hA.z >> 16));
    xA[6] = b2f((u16)(hA.w & 0xffff)); xA[7] = b2f((u16)(hA.w >> 16));
    xB[0] = b2f((u16)(hB.x & 0xffff)); xB[1] = b2f((u16)(hB.x >> 16));
    xB[2] = b2f((u16)(hB.y & 0xffff)); xB[3] = b2f((u16)(hB.y >> 16));
    xB[4] = b2f((u16)(hB.z & 0xffff)); xB[5] = b2f((u16)(hB.z >> 16));
    xB[6] = b2f((u16)(hB.w & 0xffff)); xB[7] = b2f((u16)(hB.w >> 16));
    #pragma unroll
    for (int h = 0; h < 4; ++h)
      #pragma unroll
      for (int c = 0; c < 8; ++c) {
        ac[h][c] = fmaf(aA[h], xA[c], ac[h][c]);
        ac[h][c] = fmaf(aB[h], xB[c], ac[h][c]);
      }
  }
  if (i < end) {
    int s = perm[i];
    float4 l4 = *(const float4*)(elr + (size_t)s * 32 + r * 4);
    uint4 hv = *(const uint4*)(xb + (size_t)s * 256 + hoff);
    float aa[4];
    aa[0] = __expf(leaky(l4.x + r4.x)) * rd0;
    aa[1] = __expf(leaky(l4.y + r4.y)) * rd1;
    aa[2] = __expf(leaky(l4.z + r4.z)) * rd2;
    aa[3] = __expf(leaky(l4.w + r4.w)) * rd3;
    float xv[8];
    xv[0] = b2f((u16)(hv.x & 0xffff)); xv[1] = b2f((u16)(hv.x >> 16));
    xv[2] = b2f((u16)(hv.y & 0xffff)); xv[3] = b2f((u16)(hv.y >> 16));
    xv[4] = b2f((u16)(hv.z & 0xffff)); xv[5] = b2f((u16)(hv.z >> 16));
    xv[6] = b2f((u16)(hv.w & 0xffff)); xv[7] = b2f((u16)(hv.w >> 16));
    #pragma unroll
    for (int h = 0; h < 4; ++h)
      #pragma unroll
      for (int c = 0; c < 8; ++c) ac[h][c] = fmaf(aa[h], xv[c], ac[h][c]);
  }
  // merge half-waves
  #pragma unroll
  for (int h = 0; h < 4; ++h)
    #pragma unroll
    for (int c = 0; c < 8; ++c) ac[h][c] += __shfl_xor(ac[h][c], 32);
  if (lane < 32) {
    #pragma unroll
    for (int h = 0; h < 4; ++h)
      #pragma unroll
      for (int c = 0; c < 8; ++c) sacc[w][h][lane32 * 8 + c] = ac[h][c];
  }
  __syncthreads();
  // epilogue: xaggB[h][d][rr*256+ch] = sacc[rr][h][ch] + sacc[rr+4][h][ch]
  for (int t = tid; t < 4096; t += 512) {
    int h = t >> 10, rr = (t >> 8) & 3, ch = t & 255;
    xaggB[((size_t)h * NDST + d) * 1024 + rr * 256 + ch] =
        f2b(sacc[rr][h][ch] + sacc[rr + 4][h][ch]);
  }
}

// ---------------- final combine ----------------
__global__ __launch_bounds__(256) void reduce_k(const float* __restrict__ Cagg,
                                                const float* __restrict__ Cloop,
                                                const float* __restrict__ bias,
                                                float* __restrict__ out) {
  int i = blockIdx.x * 256 + threadIdx.x;
  out[i] = fmaxf(Cagg[i] + Cloop[i] + bias[i & 255], 0.f);
}

// ---------------- launcher ----------------
extern "C" void kernel_launch(void* const* d_in, const int* in_sizes, int n_in,
                              void* d_out, int out_size, void* d_ws, size_t ws_size,
                              hipStream_t stream) {
  const float* x      = (const float*)d_in[0];
  const float* W      = (const float*)d_in[1];
  const float* attn_l = (const float*)d_in[2];
  const float* attn_r = (const float*)d_in[3];
  const float* loop_w = (const float*)d_in[4];
  const float* loop_b = (const float*)d_in[5];
  const int* edge_src = (const int*)d_in[6];
  const int* edge_dst = (const int*)d_in[7];
  float* out = (float*)d_out;

  char* wsp = (char*)d_ws;
  size_t off = 0;
  auto alloc = [&](size_t bytes) -> char* {
    char* p = wsp + off;
    off = (off + bytes + 255) & ~(size_t)255;
    return p;
  };
  u16* xb      = (u16*)alloc((size_t)NSRC * 256 * 2);        // 25.6 MB
  u16* WB      = (u16*)alloc((size_t)4 * 128 * 1024 * 2);    // 1.05 MB
  u16* WL      = (u16*)alloc((size_t)256 * 256 * 2);         // 0.13 MB
  u16* WAt     = (u16*)alloc((size_t)128 * 256 * 2);         // 65 KB
  float* elr   = (float*)alloc((size_t)NSRC * 32 * 4);       // 6.4 MB
  u16* xaggB   = (u16*)alloc((size_t)4 * NDST * 1024 * 2);   // 81.9 MB
  float* Cagg  = (float*)alloc((size_t)NDST * 256 * 4);      // 10.2 MB
  float* Cloop = (float*)alloc((size_t)NDST * 256 * 4);      // 10.2 MB
  int* counts  = (int*)alloc((size_t)NREL * NDST * 4);
  int* offs    = (int*)alloc((size_t)(NREL * NDST + 1) * 4);
  int* cursor  = (int*)alloc((size_t)NREL * NDST * 4);
  int* btot    = (int*)alloc(64 * 4);
  int* carry   = (int*)alloc(64 * 4);
  int* perm    = (int*)alloc((size_t)NREL * NEDGE * 4);      // total ~140 MB

  // conversions / weight prep
  cvtx_k<<<NSRC * 256 / 4 / 256, 256, 0, stream>>>(x, xb);
  cvtwB_k<<<2048, 256, 0, stream>>>(W, WB);
  cvtwL_k<<<256, 256, 0, stream>>>(loop_w, WL);
  wa_k<<<128, 256, 0, stream>>>(W, attn_l, attn_r, WAt);

  // CSR (all relations)
  hipMemsetAsync(counts, 0, (size_t)NREL * NDST * 4, stream);
  const int EB = (NREL * NEDGE + 255) / 256;
  hist_k<<<EB, 256, 0, stream>>>(edge_dst, counts);
  scanA_k<<<40, 1024, 0, stream>>>(counts, offs, btot);
  scanB_k<<<1, 64, 0, stream>>>(btot, carry);
  scanC_k<<<40, 1024, 0, stream>>>(offs, carry, cursor);
  scatter_k<<<EB, 256, 0, stream>>>(edge_src, edge_dst, cursor, perm);

  // elr skinny GEMM: elr[NSRC][32] f32
  gemmN_k<0, 256><<<dim3(1, (NSRC + 127) / 128), 256, 0, stream>>>(
      xb, WAt, NSRC, elr, 0);

  // fused softmax + per-head x-aggregation -> xaggB
  agg_k<<<NDST, 512, 0, stream>>>(xb, offs, perm, elr, xaggB);

  // per-head GEMMs: Cagg[d][h*64+j] = sum_r xagg_{r,h} @ 0.25*W_r[:, h*64+j]
  const int GY = (NDST + 127) / 128;
  for (int h = 0; h < 4; ++h) {
    gemmN_k<2, 1024><<<dim3(1, GY), 256, 0, stream>>>(
        xaggB + (size_t)h * NDST * 1024, WB + (size_t)h * 128 * 1024,
        NDST, Cagg, h);
  }

  // loop GEMM: Cloop = x[:NDST] @ loop_w
  gemmN_k<1, 256><<<dim3(2, GY), 256, 0, stream>>>(xb, WL, NDST, Cloop, 0);

  // out = relu(Cagg + Cloop + bias)
  reduce_k<<<NDST, 256, 0, stream>>>(Cagg, Cloop, loop_b, out);
}

// Round 7
// 274.416 us; speedup vs baseline: 1.4726x; 1.4726x over previous
//
#include <hip/hip_runtime.h>

#define NSRC 50000
#define NDST 10000
#define NEDGE 250000
#define NREL 4
#define NEG_SLOPE 0.2f
#define EMAXC 128  // cached alphas per (d,r) segment; degree is Binomial(250k,1e-4), max ~55

typedef unsigned short u16;
typedef __attribute__((ext_vector_type(8))) short bf16x8;
typedef __attribute__((ext_vector_type(4))) float f32x4;

#define GLD16(g, l) __builtin_amdgcn_global_load_lds( \
    (__attribute__((address_space(1))) void*)(void*)(g), \
    (__attribute__((address_space(3))) void*)(l), 16, 0, 0)

static __device__ __forceinline__ u16 f2b(float f) {
  unsigned u = __float_as_uint(f);
  unsigned r = (u + 0x7FFFu + ((u >> 16) & 1u)) >> 16;
  return (u16)r;
}
static __device__ __forceinline__ float b2f(u16 b) {
  return __uint_as_float((unsigned)b << 16);
}
static __device__ __forceinline__ float leaky(float x) {
  return x > 0.f ? x : NEG_SLOPE * x;
}

// ---------------- conversions ----------------
__global__ __launch_bounds__(256) void cvtx_k(const float* __restrict__ x,
                                              u16* __restrict__ xb) {
  int i = blockIdx.x * 256 + threadIdx.x;  // group of 4 elements
  float4 v = ((const float4*)x)[i];
  uint2 o;
  o.x = (unsigned)f2b(v.x) | ((unsigned)f2b(v.y) << 16);
  o.y = (unsigned)f2b(v.z) | ((unsigned)f2b(v.w) << 16);
  ((uint2*)xb)[i] = o;
}

// WBL[h][n'][k'] (bf16, n-major [4][128][1280]):
//  n'<64:  k'<1024 -> 0.25*W[k'>>8][k'&255][h*64+n'];  k'>=1024 -> loop_w[k'-1024][h*64+n']
//  n'>=64: 0
__global__ __launch_bounds__(256) void cvtwBL_k(const float* __restrict__ W,
                                                const float* __restrict__ loop_w,
                                                u16* __restrict__ WBL) {
  int g = blockIdx.x * 256 + threadIdx.x;  // 0..655359
  int h = g / 163840;
  int rem = g - h * 163840;
  int np = rem / 1280, kp = rem - np * 1280;
  float v = 0.f;
  if (np < 64) {
    if (kp < 1024)
      v = 0.25f * W[(size_t)(kp >> 8) * 65536 + (size_t)(kp & 255) * 256 + h * 64 + np];
    else
      v = loop_w[(size_t)(kp - 1024) * 256 + h * 64 + np];
  }
  WBL[g] = f2b(v);
}

// WAt[c][k] (bf16, n-major, 128 rows; rows>=32 zero):
//   c<16 : el weights  W[r]@attn_l[r]  (r=c>>2, h=c&3); 16-31: er weights
__global__ __launch_bounds__(256) void wa_k(const float* __restrict__ W,
                                            const float* __restrict__ al,
                                            const float* __restrict__ ar,
                                            u16* __restrict__ WAt) {
  int g = blockIdx.x * 256 + threadIdx.x;  // 0..32767
  int c = g >> 8, k = g & 255;
  float acc = 0.f;
  if (c < 32) {
    int cc = c & 15;
    int r = cc >> 2, h = cc & 3;
    const float* vec = ((c < 16) ? al : ar) + r * 256 + h * 64;
    const float* wrow = W + (size_t)r * 65536 + (size_t)k * 256 + h * 64;
    #pragma unroll 8
    for (int j = 0; j < 64; ++j) acc += wrow[j] * vec[j];
  }
  WAt[(size_t)c * 256 + k] = f2b(acc);
}

// ---------------- elr GEMM: elr[NSRC][32] = xb @ WAt^T ----------------
__global__ __launch_bounds__(256) void gemmE_k(const u16* __restrict__ A,
                                               const u16* __restrict__ B,
                                               float* __restrict__ outF) {
  __shared__ u16 As[128 * 64];
  __shared__ u16 Bs[128 * 64];
  const int tid = threadIdx.x;
  const int w = tid >> 6, l = tid & 63;
  const int bm = blockIdx.y * 128;
  const int wm = (w >> 1) * 64, wn = (w & 1) * 64;
  f32x4 acc[4][4] = {};
  const int lrow = l >> 3, lchunk = l & 7;

  for (int t = 0; t < 4; ++t) {
    const int k0 = t * 64;
    #pragma unroll
    for (int c = 0; c < 4; ++c) {
      int rb = (w * 4 + c) * 8;
      int row_in = rb + lrow;
      int colb = (lchunk * 16) ^ ((row_in & 7) << 4);
      long arow = bm + row_in;
      if (arow >= NSRC) arow = NSRC - 1;
      const char* ga = (const char*)A + ((size_t)arow * 256 + k0) * 2 + colb;
      GLD16(ga, (char*)As + rb * 128);
      const char* gb = (const char*)B + ((size_t)row_in * 256 + k0) * 2 + colb;
      GLD16(gb, (char*)Bs + rb * 128);
    }
    __syncthreads();
    #pragma unroll
    for (int kk = 0; kk < 2; ++kk) {
      bf16x8 af[4], bg[4];
      #pragma unroll
      for (int m = 0; m < 4; ++m) {
        int row = wm + m * 16 + (l & 15);
        int colb = (kk * 64 + ((l >> 4) * 16)) ^ ((row & 7) << 4);
        af[m] = *(const bf16x8*)((const char*)As + row * 128 + colb);
      }
      #pragma unroll
      for (int n = 0; n < 4; ++n) {
        int row = wn + n * 16 + (l & 15);
        int colb = (kk * 64 + ((l >> 4) * 16)) ^ ((row & 7) << 4);
        bg[n] = *(const bf16x8*)((const char*)Bs + row * 128 + colb);
      }
      #pragma unroll
      for (int m = 0; m < 4; ++m)
        #pragma unroll
        for (int n = 0; n < 4; ++n)
          acc[m][n] = __builtin_amdgcn_mfma_f32_16x16x32_bf16(af[m], bg[n], acc[m][n], 0, 0, 0);
    }
    __syncthreads();
  }
  #pragma unroll
  for (int m = 0; m < 4; ++m) {
    #pragma unroll
    for (int j = 0; j < 4; ++j) {
      int row = bm + wm + m * 16 + (l >> 4) * 4 + j;
      if (row < NSRC) {
        #pragma unroll
        for (int n = 0; n < 4; ++n) {
          int col = wn + n * 16 + (l & 15);
          if (col < 32) outF[(size_t)row * 32 + col] = acc[m][n][j];
        }
      }
    }
  }
}

// ---------------- fused final GEMM (per-head, z = h) ----------------
// out[d][h*64+j] = relu( sum_k xaggB[h][d][k]*WBL[h][j][k]
//                      + sum_k xb[d][k]*WBL[h][j][1024+k] + loop_b[h*64+j] )
__global__ __launch_bounds__(256) void gemmF_k(const u16* __restrict__ xaggB,
                                               const u16* __restrict__ xb,
                                               const u16* __restrict__ WBL,
                                               const float* __restrict__ loop_b,
                                               float* __restrict__ out) {
  __shared__ u16 As[128 * 64];
  __shared__ u16 Bs[128 * 64];
  const int tid = threadIdx.x;
  const int w = tid >> 6, l = tid & 63;
  const int h = blockIdx.z;
  const int bm = blockIdx.y * 128;
  const int wm = (w >> 1) * 64, wn = (w & 1) * 64;
  const u16* A1 = xaggB + (size_t)h * NDST * 1024;
  const u16* Bh = WBL + (size_t)h * 128 * 1280;
  f32x4 acc[4][4] = {};
  const int lrow = l >> 3, lchunk = l & 7;

  for (int t = 0; t < 20; ++t) {
    const int k0 = t * 64;
    #pragma unroll
    for (int c = 0; c < 4; ++c) {
      int rb = (w * 4 + c) * 8;
      int row_in = rb + lrow;
      int colb = (lchunk * 16) ^ ((row_in & 7) << 4);
      long arow = bm + row_in;
      if (arow >= NDST) arow = NDST - 1;
      const char* ga;
      if (k0 < 1024)
        ga = (const char*)A1 + ((size_t)arow * 1024 + k0) * 2 + colb;
      else
        ga = (const char*)xb + ((size_t)arow * 256 + (k0 - 1024)) * 2 + colb;
      GLD16(ga, (char*)As + rb * 128);
      const char* gb = (const char*)Bh + ((size_t)row_in * 1280 + k0) * 2 + colb;
      GLD16(gb, (char*)Bs + rb * 128);
    }
    __syncthreads();
    #pragma unroll
    for (int kk = 0; kk < 2; ++kk) {
      bf16x8 af[4], bg[4];
      #pragma unroll
      for (int m = 0; m < 4; ++m) {
        int row = wm + m * 16 + (l & 15);
        int colb = (kk * 64 + ((l >> 4) * 16)) ^ ((row & 7) << 4);
        af[m] = *(const bf16x8*)((const char*)As + row * 128 + colb);
      }
      #pragma unroll
      for (int n = 0; n < 4; ++n) {
        int row = wn + n * 16 + (l & 15);
        int colb = (kk * 64 + ((l >> 4) * 16)) ^ ((row & 7) << 4);
        bg[n] = *(const bf16x8*)((const char*)Bs + row * 128 + colb);
      }
      #pragma unroll
      for (int m = 0; m < 4; ++m)
        #pragma unroll
        for (int n = 0; n < 4; ++n)
          acc[m][n] = __builtin_amdgcn_mfma_f32_16x16x32_bf16(af[m], bg[n], acc[m][n], 0, 0, 0);
    }
    __syncthreads();
  }
  #pragma unroll
  for (int m = 0; m < 4; ++m) {
    #pragma unroll
    for (int j = 0; j < 4; ++j) {
      int row = bm + wm + m * 16 + (l >> 4) * 4 + j;
      if (row < NDST) {
        #pragma unroll
        for (int n = 0; n < 4; ++n) {
          int col = wn + n * 16 + (l & 15);
          if (col < 64)
            out[(size_t)row * 256 + h * 64 + col] =
                fmaxf(acc[m][n][j] + loop_b[h * 64 + col], 0.f);
        }
      }
    }
  }
}

// ---------------- CSR build (all 4 relations at once) ----------------
__global__ void hist_k(const int* __restrict__ edst, int* __restrict__ counts) {
  int g = blockIdx.x * 256 + threadIdx.x;
  if (g >= NREL * NEDGE) return;
  int r = g / NEDGE;
  atomicAdd(&counts[r * NDST + edst[g]], 1);
}

__global__ __launch_bounds__(1024) void scanA_k(const int* __restrict__ counts,
                                                int* __restrict__ offsets,
                                                int* __restrict__ btot) {
  __shared__ int wsum[16];
  int tid = threadIdx.x, lane = tid & 63, wid = tid >> 6;
  int i = blockIdx.x * 1024 + tid;
  int v = (i < NREL * NDST) ? counts[i] : 0;
  int x = v;
  #pragma unroll
  for (int off = 1; off < 64; off <<= 1) {
    int t = __shfl_up(x, off);
    if (lane >= off) x += t;
  }
  if (lane == 63) wsum[wid] = x;
  __syncthreads();
  if (wid == 0) {
    int t = (lane < 16) ? wsum[lane] : 0;
    #pragma unroll
    for (int off = 1; off < 16; off <<= 1) {
      int u = __shfl_up(t, off);
      if (lane >= off) t += u;
    }
    if (lane < 16) wsum[lane] = t;
  }
  __syncthreads();
  int wpre = (wid > 0) ? wsum[wid - 1] : 0;
  int incl = x + wpre;
  if (i < NREL * NDST) offsets[i] = incl - v;
  if (tid == 1023) btot[blockIdx.x] = incl;
}

__global__ void scanB_k(const int* __restrict__ btot, int* __restrict__ carry) {
  int lane = threadIdx.x;  // 64 threads = 1 wave
  int v = (lane < 40) ? btot[lane] : 0;
  int x = v;
  #pragma unroll
  for (int off = 1; off < 64; off <<= 1) {
    int t = __shfl_up(x, off);
    if (lane >= off) x += t;
  }
  if (lane < 40) carry[lane] = x - v;
}

__global__ __launch_bounds__(1024) void scanC_k(int* __restrict__ offsets,
                                                const int* __restrict__ carry,
                                                int* __restrict__ cursor) {
  int i = blockIdx.x * 1024 + threadIdx.x;
  if (i < NREL * NDST) {
    int o = offsets[i] + carry[blockIdx.x];
    offsets[i] = o;
    cursor[i] = o;
  }
  if (i == 0) offsets[NREL * NDST] = NREL * NEDGE;
}

__global__ void scatter_k(const int* __restrict__ esrc, const int* __restrict__ edst,
                          int* __restrict__ cursor, int* __restrict__ perm_src) {
  int g = blockIdx.x * 256 + threadIdx.x;
  if (g >= NREL * NEDGE) return;
  int r = g / NEDGE;
  int pos = atomicAdd(&cursor[r * NDST + edst[g]], 1);
  perm_src[pos] = esrc[g];
}

// ---------------- fused softmax + per-head x-aggregation ----------------
// Block = one dst, 256 threads = 4 waves; wave r owns segment (r,d) entirely.
// Phase A computes all edge exps, caches normalized alphas in LDS (<=128/seg).
// Phase B: lane owns 4 channels; 16 acc (4 head x 4 ch); 2-edge unroll.
// Writes xaggB[h][d][r*256+ch] (bf16) directly per wave — no cross-wave merge.
__global__ __launch_bounds__(256) void agg_k(const u16* __restrict__ xb,
                                             const int* __restrict__ offs,
                                             const int* __restrict__ perm,
                                             const float* __restrict__ elr,
                                             u16* __restrict__ xaggB) {
  __shared__ float sex[4][EMAXC][4];  // [wave][edge][head] normalized alpha
  const int d = blockIdx.x;
  const int r = threadIdx.x >> 6, lane = threadIdx.x & 63;
  const int seg = r * NDST + d;
  const int beg = offs[seg], end = offs[seg + 1];
  const int n = end - beg;
  const float4 r4 = *(const float4*)(elr + (size_t)d * 32 + 16 + r * 4);

  // phase A: denominators + exp cache
  float s0 = 0.f, s1 = 0.f, s2 = 0.f, s3 = 0.f;
  for (int e = lane; e < n; e += 64) {
    int s = perm[beg + e];
    float4 l4 = *(const float4*)(elr + (size_t)s * 32 + r * 4);
    float e0 = __expf(leaky(l4.x + r4.x));
    float e1 = __expf(leaky(l4.y + r4.y));
    float e2 = __expf(leaky(l4.z + r4.z));
    float e3 = __expf(leaky(l4.w + r4.w));
    if (e < EMAXC) *(float4*)&sex[r][e][0] = make_float4(e0, e1, e2, e3);
    s0 += e0; s1 += e1; s2 += e2; s3 += e3;
  }
  #pragma unroll
  for (int off = 1; off < 64; off <<= 1) {
    s0 += __shfl_xor(s0, off);
    s1 += __shfl_xor(s1, off);
    s2 += __shfl_xor(s2, off);
    s3 += __shfl_xor(s3, off);
  }
  const float rd0 = 1.f / fmaxf(s0, 1e-9f);
  const float rd1 = 1.f / fmaxf(s1, 1e-9f);
  const float rd2 = 1.f / fmaxf(s2, 1e-9f);
  const float rd3 = 1.f / fmaxf(s3, 1e-9f);
  // normalize cached alphas (each edge touched by exactly one lane)
  for (int e = lane; e < n && e < EMAXC; e += 64) {
    float4 v = *(const float4*)&sex[r][e][0];
    *(float4*)&sex[r][e][0] = make_float4(v.x * rd0, v.y * rd1, v.z * rd2, v.w * rd3);
  }
  __syncthreads();

  // phase B: lane owns channels [lane*4, lane*4+4)
  float ac[4][4] = {};  // [head][ch]
  const size_t xoff = (size_t)lane * 4;
  const int nc = (n < EMAXC) ? n : EMAXC;
  int e = 0;
  for (; e + 1 < nc; e += 2) {
    int sA = perm[beg + e];
    int sB = perm[beg + e + 1];
    float4 aA = *(const float4*)&sex[r][e][0];
    float4 aB = *(const float4*)&sex[r][e + 1][0];
    uint2 xA = *(const uint2*)(xb + (size_t)sA * 256 + xoff);
    uint2 xB = *(const uint2*)(xb + (size_t)sB * 256 + xoff);
    float fA0 = b2f((u16)(xA.x & 0xffff)), fA1 = b2f((u16)(xA.x >> 16));
    float fA2 = b2f((u16)(xA.y & 0xffff)), fA3 = b2f((u16)(xA.y >> 16));
    float fB0 = b2f((u16)(xB.x & 0xffff)), fB1 = b2f((u16)(xB.x >> 16));
    float fB2 = b2f((u16)(xB.y & 0xffff)), fB3 = b2f((u16)(xB.y >> 16));
    ac[0][0] = fmaf(aA.x, fA0, ac[0][0]); ac[0][1] = fmaf(aA.x, fA1, ac[0][1]);
    ac[0][2] = fmaf(aA.x, fA2, ac[0][2]); ac[0][3] = fmaf(aA.x, fA3, ac[0][3]);
    ac[1][0] = fmaf(aA.y, fA0, ac[1][0]); ac[1][1] = fmaf(aA.y, fA1, ac[1][1]);
    ac[1][2] = fmaf(aA.y, fA2, ac[1][2]); ac[1][3] = fmaf(aA.y, fA3, ac[1][3]);
    ac[2][0] = fmaf(aA.z, fA0, ac[2][0]); ac[2][1] = fmaf(aA.z, fA1, ac[2][1]);
    ac[2][2] = fmaf(aA.z, fA2, ac[2][2]); ac[2][3] = fmaf(aA.z, fA3, ac[2][3]);
    ac[3][0] = fmaf(aA.w, fA0, ac[3][0]); ac[3][1] = fmaf(aA.w, fA1, ac[3][1]);
    ac[3][2] = fmaf(aA.w, fA2, ac[3][2]); ac[3][3] = fmaf(aA.w, fA3, ac[3][3]);
    ac[0][0] = fmaf(aB.x, fB0, ac[0][0]); ac[0][1] = fmaf(aB.x, fB1, ac[0][1]);
    ac[0][2] = fmaf(aB.x, fB2, ac[0][2]); ac[0][3] = fmaf(aB.x, fB3, ac[0][3]);
    ac[1][0] = fmaf(aB.y, fB0, ac[1][0]); ac[1][1] = fmaf(aB.y, fB1, ac[1][1]);
    ac[1][2] = fmaf(aB.y, fB2, ac[1][2]); ac[1][3] = fmaf(aB.y, fB3, ac[1][3]);
    ac[2][0] = fmaf(aB.z, fB0, ac[2][0]); ac[2][1] = fmaf(aB.z, fB1, ac[2][1]);
    ac[2][2] = fmaf(aB.z, fB2, ac[2][2]); ac[2][3] = fmaf(aB.z, fB3, ac[2][3]);
    ac[3][0] = fmaf(aB.w, fB0, ac[3][0]); ac[3][1] = fmaf(aB.w, fB1, ac[3][1]);
    ac[3][2] = fmaf(aB.w, fB2, ac[3][2]); ac[3][3] = fmaf(aB.w, fB3, ac[3][3]);
  }
  if (e < nc) {
    int s = perm[beg + e];
    float4 aa = *(const float4*)&sex[r][e][0];
    uint2 xv = *(const uint2*)(xb + (size_t)s * 256 + xoff);
    float f0 = b2f((u16)(xv.x & 0xffff)), f1 = b2f((u16)(xv.x >> 16));
    float f2 = b2f((u16)(xv.y & 0xffff)), f3 = b2f((u16)(xv.y >> 16));
    ac[0][0] = fmaf(aa.x, f0, ac[0][0]); ac[0][1] = fmaf(aa.x, f1, ac[0][1]);
    ac[0][2] = fmaf(aa.x, f2, ac[0][2]); ac[0][3] = fmaf(aa.x, f3, ac[0][3]);
    ac[1][0] = fmaf(aa.y, f0, ac[1][0]); ac[1][1] = fmaf(aa.y, f1, ac[1][1]);
    ac[1][2] = fmaf(aa.y, f2, ac[1][2]); ac[1][3] = fmaf(aa.y, f3, ac[1][3]);
    ac[2][0] = fmaf(aa.z, f0, ac[2][0]); ac[2][1] = fmaf(aa.z, f1, ac[2][1]);
    ac[2][2] = fmaf(aa.z, f2, ac[2][2]); ac[2][3] = fmaf(aa.z, f3, ac[2][3]);
    ac[3][0] = fmaf(aa.w, f0, ac[3][0]); ac[3][1] = fmaf(aa.w, f1, ac[3][1]);
    ac[3][2] = fmaf(aa.w, f2, ac[3][2]); ac[3][3] = fmaf(aa.w, f3, ac[3][3]);
  }
  // overflow path (degree > EMAXC; essentially never for this graph)
  for (int i = EMAXC; i < n; ++i) {
    int s = perm[beg + i];
    float4 l4 = *(const float4*)(elr + (size_t)s * 32 + r * 4);
    float a0 = __expf(leaky(l4.x + r4.x)) * rd0;
    float a1 = __expf(leaky(l4.y + r4.y)) * rd1;
    float a2 = __expf(leaky(l4.z + r4.z)) * rd2;
    float a3 = __expf(leaky(l4.w + r4.w)) * rd3;
    uint2 xv = *(const uint2*)(xb + (size_t)s * 256 + xoff);
    float f0 = b2f((u16)(xv.x & 0xffff)), f1 = b2f((u16)(xv.x >> 16));
    float f2 = b2f((u16)(xv.y & 0xffff)), f3 = b2f((u16)(xv.y >> 16));
    ac[0][0] = fmaf(a0, f0, ac[0][0]); ac[0][1] = fmaf(a0, f1, ac[0][1]);
    ac[0][2] = fmaf(a0, f2, ac[0][2]); ac[0][3] = fmaf(a0, f3, ac[0][3]);
    ac[1][0] = fmaf(a1, f0, ac[1][0]); ac[1][1] = fmaf(a1, f1, ac[1][1]);
    ac[1][2] = fmaf(a1, f2, ac[1][2]); ac[1][3] = fmaf(a1, f3, ac[1][3]);
    ac[2][0] = fmaf(a2, f0, ac[2][0]); ac[2][1] = fmaf(a2, f1, ac[2][1]);
    ac[2][2] = fmaf(a2, f2, ac[2][2]); ac[2][3] = fmaf(a2, f3, ac[2][3]);
    ac[3][0] = fmaf(a3, f0, ac[3][0]); ac[3][1] = fmaf(a3, f1, ac[3][1]);
    ac[3][2] = fmaf(a3, f2, ac[3][2]); ac[3][3] = fmaf(a3, f3, ac[3][3]);
  }

  // direct write: xaggB[h][d][r*256 + lane*4 ..]
  #pragma unroll
  for (int h = 0; h < 4; ++h) {
    uint2 o;
    o.x = (unsigned)f2b(ac[h][0]) | ((unsigned)f2b(ac[h][1]) << 16);
    o.y = (unsigned)f2b(ac[h][2]) | ((unsigned)f2b(ac[h][3]) << 16);
    *(uint2*)(xaggB + ((size_t)h * NDST + d) * 1024 + (size_t)r * 256 + xoff) = o;
  }
}

// ---------------- launcher ----------------
extern "C" void kernel_launch(void* const* d_in, const int* in_sizes, int n_in,
                              void* d_out, int out_size, void* d_ws, size_t ws_size,
                              hipStream_t stream) {
  const float* x      = (const float*)d_in[0];
  const float* W      = (const float*)d_in[1];
  const float* attn_l = (const float*)d_in[2];
  const float* attn_r = (const float*)d_in[3];
  const float* loop_w = (const float*)d_in[4];
  const float* loop_b = (const float*)d_in[5];
  const int* edge_src = (const int*)d_in[6];
  const int* edge_dst = (const int*)d_in[7];
  float* out = (float*)d_out;

  char* wsp = (char*)d_ws;
  size_t off = 0;
  auto alloc = [&](size_t bytes) -> char* {
    char* p = wsp + off;
    off = (off + bytes + 255) & ~(size_t)255;
    return p;
  };
  u16* xb      = (u16*)alloc((size_t)NSRC * 256 * 2);        // 25.6 MB
  u16* WBL     = (u16*)alloc((size_t)4 * 128 * 1280 * 2);    // 1.3 MB
  u16* WAt     = (u16*)alloc((size_t)128 * 256 * 2);         // 65 KB
  float* elr   = (float*)alloc((size_t)NSRC * 32 * 4);       // 6.4 MB
  u16* xaggB   = (u16*)alloc((size_t)4 * NDST * 1024 * 2);   // 81.9 MB
  int* counts  = (int*)alloc((size_t)NREL * NDST * 4);
  int* offs    = (int*)alloc((size_t)(NREL * NDST + 1) * 4);
  int* cursor  = (int*)alloc((size_t)NREL * NDST * 4);
  int* btot    = (int*)alloc(64 * 4);
  int* carry   = (int*)alloc(64 * 4);
  int* perm    = (int*)alloc((size_t)NREL * NEDGE * 4);      // total ~120 MB

  // conversions / weight prep
  cvtx_k<<<NSRC * 256 / 4 / 256, 256, 0, stream>>>(x, xb);
  cvtwBL_k<<<2560, 256, 0, stream>>>(W, loop_w, WBL);
  wa_k<<<128, 256, 0, stream>>>(W, attn_l, attn_r, WAt);

  // CSR (all relations)
  hipMemsetAsync(counts, 0, (size_t)NREL * NDST * 4, stream);
  const int EB = (NREL * NEDGE + 255) / 256;
  hist_k<<<EB, 256, 0, stream>>>(edge_dst, counts);
  scanA_k<<<40, 1024, 0, stream>>>(counts, offs, btot);
  scanB_k<<<1, 64, 0, stream>>>(btot, carry);
  scanC_k<<<40, 1024, 0, stream>>>(offs, carry, cursor);
  scatter_k<<<EB, 256, 0, stream>>>(edge_src, edge_dst, cursor, perm);

  // elr skinny GEMM: elr[NSRC][32] f32
  gemmE_k<<<dim3(1, (NSRC + 127) / 128), 256, 0, stream>>>(xb, WAt, elr);

  // fused softmax + per-head x-aggregation -> xaggB
  agg_k<<<NDST, 256, 0, stream>>>(xb, offs, perm, elr, xaggB);

  // fused final: out = relu([xagg_h | xb] @ WBL_h^T + loop_b), one launch, z = head
  gemmF_k<<<dim3(1, (NDST + 127) / 128, 4), 256, 0, stream>>>(
      xaggB, xb, WBL, loop_b, out);
}

// Round 8
// 235.929 us; speedup vs baseline: 1.7129x; 1.1631x over previous
//
#include <hip/hip_runtime.h>

#define NSRC 50000
#define NDST 10000
#define NEDGE 250000
#define NREL 4
#define NEG_SLOPE 0.2f
#define EMAXC 128  // cached alphas per (d,r) segment; degree Binomial(250k,1e-4), max ~55

typedef unsigned short u16;
typedef __attribute__((ext_vector_type(8))) short bf16x8;
typedef __attribute__((ext_vector_type(4))) float f32x4;
typedef __attribute__((ext_vector_type(2))) float f32x2;

#define GLD16(g, l) __builtin_amdgcn_global_load_lds( \
    (__attribute__((address_space(1))) void*)(void*)(g), \
    (__attribute__((address_space(3))) void*)(l), 16, 0, 0)

static __device__ __forceinline__ u16 f2b(float f) {
  unsigned u = __float_as_uint(f);
  unsigned r = (u + 0x7FFFu + ((u >> 16) & 1u)) >> 16;
  return (u16)r;
}
static __device__ __forceinline__ float b2f(u16 b) {
  return __uint_as_float((unsigned)b << 16);
}
static __device__ __forceinline__ float leaky(float x) {
  return x > 0.f ? x : NEG_SLOPE * x;
}

// ---------- fp8 e4m3 (OCP) helpers ----------
static __device__ __forceinline__ unsigned enc8_sw(float f) {
  unsigned s = (__float_as_uint(f) >> 24) & 0x80u;
  float a = fminf(fabsf(f), 448.f);
  unsigned em;
  if (a < 0x1p-6f) {
    em = (unsigned)rintf(a * 512.f);  // subnormal (and exact 2^-6 boundary)
  } else {
    unsigned ab = __float_as_uint(a);
    unsigned lsb = (ab >> 20) & 1u;
    ab += 0x7FFFFu + lsb;             // RNE to 3 mantissa bits
    int e = (int)(ab >> 23) - 127;
    unsigned m = (ab >> 20) & 7u;
    em = (unsigned)((e + 7) << 3) | m;
    if (em > 0x7Eu) em = 0x7Eu;       // clamp to 448
  }
  return s | em;
}
static __device__ __forceinline__ float dec8_sw(unsigned b) {
  unsigned s = b & 0x80u;
  unsigned em = b & 0x7Fu;
  float n = __uint_as_float((s << 24) | ((em << 20) + 0x3C000000u));
  float sub = (s ? -1.f : 1.f) * (float)em * 0x1p-9f;
  return em >= 8 ? n : sub;
}
static __device__ __forceinline__ unsigned enc4(float a, float b, float c, float d) {
#if __has_builtin(__builtin_amdgcn_cvt_pk_fp8_f32)
  int q = __builtin_amdgcn_cvt_pk_fp8_f32(a, b, 0, 0);
  q = __builtin_amdgcn_cvt_pk_fp8_f32(c, d, q, 1);
  return (unsigned)q;
#else
  return enc8_sw(a) | (enc8_sw(b) << 8) | (enc8_sw(c) << 16) | (enc8_sw(d) << 24);
#endif
}
static __device__ __forceinline__ void dec4(unsigned q, float f[4]) {
#if __has_builtin(__builtin_amdgcn_cvt_pk_f32_fp8)
  f32x2 lo = __builtin_amdgcn_cvt_pk_f32_fp8((int)q, 0);
  f32x2 hi = __builtin_amdgcn_cvt_pk_f32_fp8((int)q, 1);
  f[0] = lo.x; f[1] = lo.y; f[2] = hi.x; f[3] = hi.y;
#else
  f[0] = dec8_sw(q & 0xff); f[1] = dec8_sw((q >> 8) & 0xff);
  f[2] = dec8_sw((q >> 16) & 0xff); f[3] = dec8_sw(q >> 24);
#endif
}

// ---------------- merged prep: cvtx(+fp8) | cvtwBL | wa | hist ----------------
#define PB_CVTX 12500
#define PB_WBL  1280   // 4*64*1280/256
#define PB_WA   128
#define PB_HIST 3907
__global__ __launch_bounds__(256) void prep_k(const float* __restrict__ x,
                                              const float* __restrict__ W,
                                              const float* __restrict__ loop_w,
                                              const float* __restrict__ al,
                                              const float* __restrict__ ar,
                                              const int* __restrict__ edst,
                                              u16* __restrict__ xb,
                                              unsigned* __restrict__ xq,
                                              u16* __restrict__ WBL,
                                              u16* __restrict__ WAt,
                                              int* __restrict__ counts) {
  int bi = blockIdx.x;
  int tid = threadIdx.x;
  if (bi < PB_CVTX) {
    int i = bi * 256 + tid;  // group of 4 elements
    float4 v = ((const float4*)x)[i];
    uint2 o;
    o.x = (unsigned)f2b(v.x) | ((unsigned)f2b(v.y) << 16);
    o.y = (unsigned)f2b(v.z) | ((unsigned)f2b(v.w) << 16);
    ((uint2*)xb)[i] = o;
    xq[i] = enc4(v.x, v.y, v.z, v.w);
  } else if (bi < PB_CVTX + PB_WBL) {
    // WBL[h][n(64)][k'(1280)]: k'<1024 -> 0.25*W[k'>>8][k'&255][h*64+n]; else loop_w
    int g = (bi - PB_CVTX) * 256 + tid;
    int h = g / 81920, rem = g - h * 81920;
    int np = rem / 1280, kp = rem - np * 1280;
    float v;
    if (kp < 1024)
      v = 0.25f * W[(size_t)(kp >> 8) * 65536 + (size_t)(kp & 255) * 256 + h * 64 + np];
    else
      v = loop_w[(size_t)(kp - 1024) * 256 + h * 64 + np];
    WBL[g] = f2b(v);
  } else if (bi < PB_CVTX + PB_WBL + PB_WA) {
    int g = (bi - PB_CVTX - PB_WBL) * 256 + tid;
    int c = g >> 8, k = g & 255;
    float acc = 0.f;
    if (c < 32) {
      int cc = c & 15;
      int r = cc >> 2, h = cc & 3;
      const float* vec = ((c < 16) ? al : ar) + r * 256 + h * 64;
      const float* wrow = W + (size_t)r * 65536 + (size_t)k * 256 + h * 64;
      #pragma unroll 8
      for (int j = 0; j < 64; ++j) acc += wrow[j] * vec[j];
    }
    WAt[(size_t)c * 256 + k] = f2b(acc);
  } else {
    int g = (bi - PB_CVTX - PB_WBL - PB_WA) * 256 + tid;
    if (g < NREL * NEDGE) {
      int r = g / NEDGE;
      atomicAdd(&counts[r * NDST + edst[g]], 1);
    }
  }
}

// ---------------- elr GEMM: elr[NSRC][32] = xb @ WAt^T ----------------
__global__ __launch_bounds__(256) void gemmE_k(const u16* __restrict__ A,
                                               const u16* __restrict__ B,
                                               float* __restrict__ outF) {
  __shared__ u16 As[128 * 64];
  __shared__ u16 Bs[128 * 64];
  const int tid = threadIdx.x;
  const int w = tid >> 6, l = tid & 63;
  const int bm = blockIdx.y * 128;
  const int wm = (w >> 1) * 64, wn = (w & 1) * 64;
  f32x4 acc[4][4] = {};
  const int lrow = l >> 3, lchunk = l & 7;

  for (int t = 0; t < 4; ++t) {
    const int k0 = t * 64;
    #pragma unroll
    for (int c = 0; c < 4; ++c) {
      int rb = (w * 4 + c) * 8;
      int row_in = rb + lrow;
      int colb = (lchunk * 16) ^ ((row_in & 7) << 4);
      long arow = bm + row_in;
      if (arow >= NSRC) arow = NSRC - 1;
      const char* ga = (const char*)A + ((size_t)arow * 256 + k0) * 2 + colb;
      GLD16(ga, (char*)As + rb * 128);
      const char* gb = (const char*)B + ((size_t)row_in * 256 + k0) * 2 + colb;
      GLD16(gb, (char*)Bs + rb * 128);
    }
    __syncthreads();
    #pragma unroll
    for (int kk = 0; kk < 2; ++kk) {
      bf16x8 af[4], bg[4];
      #pragma unroll
      for (int m = 0; m < 4; ++m) {
        int row = wm + m * 16 + (l & 15);
        int colb = (kk * 64 + ((l >> 4) * 16)) ^ ((row & 7) << 4);
        af[m] = *(const bf16x8*)((const char*)As + row * 128 + colb);
      }
      #pragma unroll
      for (int n = 0; n < 4; ++n) {
        int row = wn + n * 16 + (l & 15);
        int colb = (kk * 64 + ((l >> 4) * 16)) ^ ((row & 7) << 4);
        bg[n] = *(const bf16x8*)((const char*)Bs + row * 128 + colb);
      }
      #pragma unroll
      for (int m = 0; m < 4; ++m)
        #pragma unroll
        for (int n = 0; n < 4; ++n)
          acc[m][n] = __builtin_amdgcn_mfma_f32_16x16x32_bf16(af[m], bg[n], acc[m][n], 0, 0, 0);
    }
    __syncthreads();
  }
  #pragma unroll
  for (int m = 0; m < 4; ++m) {
    #pragma unroll
    for (int j = 0; j < 4; ++j) {
      int row = bm + wm + m * 16 + (l >> 4) * 4 + j;
      if (row < NSRC) {
        #pragma unroll
        for (int n = 0; n < 4; ++n) {
          int col = wn + n * 16 + (l & 15);
          if (col < 32) outF[(size_t)row * 32 + col] = acc[m][n][j];
        }
      }
    }
  }
}

// ---------------- fused final GEMM, full-util N=64 tile (z = head) ----------------
// out[d][h*64+j] = relu( [xagg_h(1024) | xb(256)] @ WBL[h][j][.] + loop_b[h*64+j] )
// Block 256thr = 4 waves; tile M=128 (wave owns 32 rows), N=64, K=1280.
__global__ __launch_bounds__(256) void gemmF_k(const u16* __restrict__ xaggB,
                                               const u16* __restrict__ xb,
                                               const u16* __restrict__ WBL,
                                               const float* __restrict__ loop_b,
                                               float* __restrict__ out) {
  __shared__ u16 As[128 * 64];
  __shared__ u16 Bs[64 * 64];
  const int tid = threadIdx.x;
  const int w = tid >> 6, l = tid & 63;
  const int h = blockIdx.z;
  const int bm = blockIdx.y * 128;
  const int wm = w * 32;
  const u16* A1 = xaggB + (size_t)h * NDST * 1024;
  const u16* Bh = WBL + (size_t)h * 64 * 1280;
  f32x4 acc[2][4] = {};
  const int lrow = l >> 3, lchunk = l & 7;

  for (int t = 0; t < 20; ++t) {
    const int k0 = t * 64;
    #pragma unroll
    for (int c = 0; c < 4; ++c) {
      int rb = (w * 4 + c) * 8;
      int row_in = rb + lrow;
      int colb = (lchunk * 16) ^ ((row_in & 7) << 4);
      long arow = bm + row_in;
      if (arow >= NDST) arow = NDST - 1;
      const char* ga;
      if (k0 < 1024)
        ga = (const char*)A1 + ((size_t)arow * 1024 + k0) * 2 + colb;
      else
        ga = (const char*)xb + ((size_t)arow * 256 + (k0 - 1024)) * 2 + colb;
      GLD16(ga, (char*)As + rb * 128);
    }
    #pragma unroll
    for (int c = 0; c < 2; ++c) {
      int rb = (w * 2 + c) * 8;
      int row_in = rb + lrow;
      int colb = (lchunk * 16) ^ ((row_in & 7) << 4);
      const char* gb = (const char*)Bh + ((size_t)row_in * 1280 + k0) * 2 + colb;
      GLD16(gb, (char*)Bs + rb * 128);
    }
    __syncthreads();
    #pragma unroll
    for (int kk = 0; kk < 2; ++kk) {
      bf16x8 af[2], bg[4];
      #pragma unroll
      for (int m = 0; m < 2; ++m) {
        int row = wm + m * 16 + (l & 15);
        int colb = (kk * 64 + ((l >> 4) * 16)) ^ ((row & 7) << 4);
        af[m] = *(const bf16x8*)((const char*)As + row * 128 + colb);
      }
      #pragma unroll
      for (int n = 0; n < 4; ++n) {
        int row = n * 16 + (l & 15);
        int colb = (kk * 64 + ((l >> 4) * 16)) ^ ((row & 7) << 4);
        bg[n] = *(const bf16x8*)((const char*)Bs + row * 128 + colb);
      }
      #pragma unroll
      for (int m = 0; m < 2; ++m)
        #pragma unroll
        for (int n = 0; n < 4; ++n)
          acc[m][n] = __builtin_amdgcn_mfma_f32_16x16x32_bf16(af[m], bg[n], acc[m][n], 0, 0, 0);
    }
    __syncthreads();
  }
  #pragma unroll
  for (int m = 0; m < 2; ++m) {
    #pragma unroll
    for (int j = 0; j < 4; ++j) {
      int row = bm + wm + m * 16 + (l >> 4) * 4 + j;
      if (row < NDST) {
        #pragma unroll
        for (int n = 0; n < 4; ++n) {
          int col = n * 16 + (l & 15);
          out[(size_t)row * 256 + h * 64 + col] =
              fmaxf(acc[m][n][j] + loop_b[h * 64 + col], 0.f);
        }
      }
    }
  }
}

// ---------------- CSR scans / scatter ----------------
__global__ __launch_bounds__(1024) void scanA_k(const int* __restrict__ counts,
                                                int* __restrict__ offsets,
                                                int* __restrict__ btot) {
  __shared__ int wsum[16];
  int tid = threadIdx.x, lane = tid & 63, wid = tid >> 6;
  int i = blockIdx.x * 1024 + tid;
  int v = (i < NREL * NDST) ? counts[i] : 0;
  int x = v;
  #pragma unroll
  for (int off = 1; off < 64; off <<= 1) {
    int t = __shfl_up(x, off);
    if (lane >= off) x += t;
  }
  if (lane == 63) wsum[wid] = x;
  __syncthreads();
  if (wid == 0) {
    int t = (lane < 16) ? wsum[lane] : 0;
    #pragma unroll
    for (int off = 1; off < 16; off <<= 1) {
      int u = __shfl_up(t, off);
      if (lane >= off) t += u;
    }
    if (lane < 16) wsum[lane] = t;
  }
  __syncthreads();
  int wpre = (wid > 0) ? wsum[wid - 1] : 0;
  int incl = x + wpre;
  if (i < NREL * NDST) offsets[i] = incl - v;
  if (tid == 1023) btot[blockIdx.x] = incl;
}

__global__ void scanB_k(const int* __restrict__ btot, int* __restrict__ carry) {
  int lane = threadIdx.x;  // 64 threads = 1 wave
  int v = (lane < 40) ? btot[lane] : 0;
  int x = v;
  #pragma unroll
  for (int off = 1; off < 64; off <<= 1) {
    int t = __shfl_up(x, off);
    if (lane >= off) x += t;
  }
  if (lane < 40) carry[lane] = x - v;
}

__global__ __launch_bounds__(1024) void scanC_k(int* __restrict__ offsets,
                                                const int* __restrict__ carry,
                                                int* __restrict__ cursor) {
  int i = blockIdx.x * 1024 + threadIdx.x;
  if (i < NREL * NDST) {
    int o = offsets[i] + carry[blockIdx.x];
    offsets[i] = o;
    cursor[i] = o;
  }
  if (i == 0) offsets[NREL * NDST] = NREL * NEDGE;
}

__global__ void scatter_k(const int* __restrict__ esrc, const int* __restrict__ edst,
                          int* __restrict__ cursor, int* __restrict__ perm_src) {
  int g = blockIdx.x * 256 + threadIdx.x;
  if (g >= NREL * NEDGE) return;
  int r = g / NEDGE;
  int pos = atomicAdd(&cursor[r * NDST + edst[g]], 1);
  perm_src[pos] = esrc[g];
}

// ---------------- fused softmax + per-head x-aggregation (fp8 gather) ----------------
// Block = one dst, 4 waves; wave r owns segment (r,d). LDS alpha-cache; phase B
// gathers 256B fp8 x-rows, 4-edge unroll; lane owns 4 ch x 4 head acc.
static __device__ __forceinline__ void edge_fma(float (&ac)[4][4], float4 a4, unsigned q) {
  float f[4];
  dec4(q, f);
  const float ah[4] = {a4.x, a4.y, a4.z, a4.w};
  #pragma unroll
  for (int h = 0; h < 4; ++h)
    #pragma unroll
    for (int c = 0; c < 4; ++c)
      ac[h][c] = fmaf(ah[h], f[c], ac[h][c]);
}

__global__ __launch_bounds__(256) void agg_k(const unsigned* __restrict__ xq,
                                             const int* __restrict__ offs,
                                             const int* __restrict__ perm,
                                             const float* __restrict__ elr,
                                             u16* __restrict__ xaggB) {
  __shared__ float sex[4][EMAXC][4];  // [wave][edge][head] normalized alpha
  const int d = blockIdx.x;
  const int r = threadIdx.x >> 6, lane = threadIdx.x & 63;
  const int seg = r * NDST + d;
  const int beg = offs[seg], end = offs[seg + 1];
  const int n = end - beg;
  const float4 r4 = *(const float4*)(elr + (size_t)d * 32 + 16 + r * 4);

  // phase A: denominators + exp cache
  float s0 = 0.f, s1 = 0.f, s2 = 0.f, s3 = 0.f;
  for (int e = lane; e < n; e += 64) {
    int s = perm[beg + e];
    float4 l4 = *(const float4*)(elr + (size_t)s * 32 + r * 4);
    float e0 = __expf(leaky(l4.x + r4.x));
    float e1 = __expf(leaky(l4.y + r4.y));
    float e2 = __expf(leaky(l4.z + r4.z));
    float e3 = __expf(leaky(l4.w + r4.w));
    if (e < EMAXC) *(float4*)&sex[r][e][0] = make_float4(e0, e1, e2, e3);
    s0 += e0; s1 += e1; s2 += e2; s3 += e3;
  }
  #pragma unroll
  for (int off = 1; off < 64; off <<= 1) {
    s0 += __shfl_xor(s0, off);
    s1 += __shfl_xor(s1, off);
    s2 += __shfl_xor(s2, off);
    s3 += __shfl_xor(s3, off);
  }
  const float rd0 = 1.f / fmaxf(s0, 1e-9f);
  const float rd1 = 1.f / fmaxf(s1, 1e-9f);
  const float rd2 = 1.f / fmaxf(s2, 1e-9f);
  const float rd3 = 1.f / fmaxf(s3, 1e-9f);
  for (int e = lane; e < n && e < EMAXC; e += 64) {
    float4 v = *(const float4*)&sex[r][e][0];
    *(float4*)&sex[r][e][0] = make_float4(v.x * rd0, v.y * rd1, v.z * rd2, v.w * rd3);
  }
  __syncthreads();

  // phase B: lane owns channels [lane*4, lane*4+4); 4-edge unroll
  float ac[4][4] = {};  // [head][ch]
  const int nc = (n < EMAXC) ? n : EMAXC;
  int e = 0;
  for (; e + 3 < nc; e += 4) {
    int sA = perm[beg + e], sB = perm[beg + e + 1];
    int sC = perm[beg + e + 2], sD = perm[beg + e + 3];
    float4 aA = *(const float4*)&sex[r][e][0];
    float4 aB = *(const float4*)&sex[r][e + 1][0];
    float4 aC = *(const float4*)&sex[r][e + 2][0];
    float4 aD = *(const float4*)&sex[r][e + 3][0];
    unsigned qA = xq[(size_t)sA * 64 + lane];
    unsigned qB = xq[(size_t)sB * 64 + lane];
    unsigned qC = xq[(size_t)sC * 64 + lane];
    unsigned qD = xq[(size_t)sD * 64 + lane];
    edge_fma(ac, aA, qA);
    edge_fma(ac, aB, qB);
    edge_fma(ac, aC, qC);
    edge_fma(ac, aD, qD);
  }
  for (; e < nc; ++e) {
    int s = perm[beg + e];
    float4 aa = *(const float4*)&sex[r][e][0];
    unsigned q = xq[(size_t)s * 64 + lane];
    edge_fma(ac, aa, q);
  }
  // overflow path (degree > EMAXC; essentially never for this graph)
  for (int i = EMAXC; i < n; ++i) {
    int s = perm[beg + i];
    float4 l4 = *(const float4*)(elr + (size_t)s * 32 + r * 4);
    float4 aa;
    aa.x = __expf(leaky(l4.x + r4.x)) * rd0;
    aa.y = __expf(leaky(l4.y + r4.y)) * rd1;
    aa.z = __expf(leaky(l4.z + r4.z)) * rd2;
    aa.w = __expf(leaky(l4.w + r4.w)) * rd3;
    unsigned q = xq[(size_t)s * 64 + lane];
    edge_fma(ac, aa, q);
  }

  // direct write: xaggB[h][d][r*256 + lane*4 ..]
  #pragma unroll
  for (int h = 0; h < 4; ++h) {
    uint2 o;
    o.x = (unsigned)f2b(ac[h][0]) | ((unsigned)f2b(ac[h][1]) << 16);
    o.y = (unsigned)f2b(ac[h][2]) | ((unsigned)f2b(ac[h][3]) << 16);
    *(uint2*)(xaggB + ((size_t)h * NDST + d) * 1024 + (size_t)r * 256 + (size_t)lane * 4) = o;
  }
}

// ---------------- launcher ----------------
extern "C" void kernel_launch(void* const* d_in, const int* in_sizes, int n_in,
                              void* d_out, int out_size, void* d_ws, size_t ws_size,
                              hipStream_t stream) {
  const float* x      = (const float*)d_in[0];
  const float* W      = (const float*)d_in[1];
  const float* attn_l = (const float*)d_in[2];
  const float* attn_r = (const float*)d_in[3];
  const float* loop_w = (const float*)d_in[4];
  const float* loop_b = (const float*)d_in[5];
  const int* edge_src = (const int*)d_in[6];
  const int* edge_dst = (const int*)d_in[7];
  float* out = (float*)d_out;

  char* wsp = (char*)d_ws;
  size_t off = 0;
  auto alloc = [&](size_t bytes) -> char* {
    char* p = wsp + off;
    off = (off + bytes + 255) & ~(size_t)255;
    return p;
  };
  u16* xb      = (u16*)alloc((size_t)NSRC * 256 * 2);        // 25.6 MB
  unsigned* xq = (unsigned*)alloc((size_t)NSRC * 64 * 4);    // 12.8 MB (fp8)
  u16* WBL     = (u16*)alloc((size_t)4 * 64 * 1280 * 2);     // 0.66 MB
  u16* WAt     = (u16*)alloc((size_t)128 * 256 * 2);         // 65 KB
  float* elr   = (float*)alloc((size_t)NSRC * 32 * 4);       // 6.4 MB
  u16* xaggB   = (u16*)alloc((size_t)4 * NDST * 1024 * 2);   // 81.9 MB
  int* counts  = (int*)alloc((size_t)NREL * NDST * 4);
  int* offs    = (int*)alloc((size_t)(NREL * NDST + 1) * 4);
  int* cursor  = (int*)alloc((size_t)NREL * NDST * 4);
  int* btot    = (int*)alloc(64 * 4);
  int* carry   = (int*)alloc(64 * 4);
  int* perm    = (int*)alloc((size_t)NREL * NEDGE * 4);      // total ~136 MB

  hipMemsetAsync(counts, 0, (size_t)NREL * NDST * 4, stream);

  // merged prep: cvtx(+fp8) | WBL | WAt | hist
  prep_k<<<PB_CVTX + PB_WBL + PB_WA + PB_HIST, 256, 0, stream>>>(
      x, W, loop_w, attn_l, attn_r, edge_dst, xb, xq, WBL, WAt, counts);

  scanA_k<<<40, 1024, 0, stream>>>(counts, offs, btot);
  scanB_k<<<1, 64, 0, stream>>>(btot, carry);
  scanC_k<<<40, 1024, 0, stream>>>(offs, carry, cursor);
  scatter_k<<<(NREL * NEDGE + 255) / 256, 256, 0, stream>>>(
      edge_src, edge_dst, cursor, perm);

  // elr skinny GEMM: elr[NSRC][32] f32
  gemmE_k<<<dim3(1, (NSRC + 127) / 128), 256, 0, stream>>>(xb, WAt, elr);

  // fused softmax + per-head x-aggregation (fp8 gather) -> xaggB
  agg_k<<<NDST, 256, 0, stream>>>(xq, offs, perm, elr, xaggB);

  // fused final: out = relu([xagg_h | xb] @ WBL_h^T + loop_b), z = head
  gemmF_k<<<dim3(1, (NDST + 127) / 128, 4), 256, 0, stream>>>(
      xaggB, xb, WBL, loop_b, out);
}

// Round 9
// 234.843 us; speedup vs baseline: 1.7208x; 1.0046x over previous
//
#include <hip/hip_runtime.h>

#define NSRC 50000
#define NDST 10000
#define NEDGE 250000
#define NREL 4
#define NEG_SLOPE 0.2f
#define EMAXC 128  // cached alphas per (d,r) segment; degree Binomial(250k,1e-4), max ~55

typedef unsigned short u16;
typedef __attribute__((ext_vector_type(8))) short bf16x8;
typedef __attribute__((ext_vector_type(4))) float f32x4;
typedef __attribute__((ext_vector_type(2))) float f32x2;

#define GLD16(g, l) __builtin_amdgcn_global_load_lds( \
    (__attribute__((address_space(1))) void*)(void*)(g), \
    (__attribute__((address_space(3))) void*)(l), 16, 0, 0)

static __device__ __forceinline__ u16 f2b(float f) {
  unsigned u = __float_as_uint(f);
  unsigned r = (u + 0x7FFFu + ((u >> 16) & 1u)) >> 16;
  return (u16)r;
}
static __device__ __forceinline__ float b2f(u16 b) {
  return __uint_as_float((unsigned)b << 16);
}
static __device__ __forceinline__ float leaky(float x) {
  return x > 0.f ? x : NEG_SLOPE * x;
}

// ---------- fp8 e4m3 (OCP) helpers ----------
static __device__ __forceinline__ unsigned enc8_sw(float f) {
  unsigned s = (__float_as_uint(f) >> 24) & 0x80u;
  float a = fminf(fabsf(f), 448.f);
  unsigned em;
  if (a < 0x1p-6f) {
    em = (unsigned)rintf(a * 512.f);  // subnormal (and exact 2^-6 boundary)
  } else {
    unsigned ab = __float_as_uint(a);
    unsigned lsb = (ab >> 20) & 1u;
    ab += 0x7FFFFu + lsb;             // RNE to 3 mantissa bits
    int e = (int)(ab >> 23) - 127;
    unsigned m = (ab >> 20) & 7u;
    em = (unsigned)((e + 7) << 3) | m;
    if (em > 0x7Eu) em = 0x7Eu;       // clamp to 448
  }
  return s | em;
}
static __device__ __forceinline__ float dec8_sw(unsigned b) {
  unsigned s = b & 0x80u;
  unsigned em = b & 0x7Fu;
  float n = __uint_as_float((s << 24) | ((em << 20) + 0x3C000000u));
  float sub = (s ? -1.f : 1.f) * (float)em * 0x1p-9f;
  return em >= 8 ? n : sub;
}
static __device__ __forceinline__ unsigned enc4(float a, float b, float c, float d) {
#if __has_builtin(__builtin_amdgcn_cvt_pk_fp8_f32)
  int q = __builtin_amdgcn_cvt_pk_fp8_f32(a, b, 0, 0);
  q = __builtin_amdgcn_cvt_pk_fp8_f32(c, d, q, 1);
  return (unsigned)q;
#else
  return enc8_sw(a) | (enc8_sw(b) << 8) | (enc8_sw(c) << 16) | (enc8_sw(d) << 24);
#endif
}
static __device__ __forceinline__ void dec4(unsigned q, float f[4]) {
#if __has_builtin(__builtin_amdgcn_cvt_pk_f32_fp8)
  f32x2 lo = __builtin_amdgcn_cvt_pk_f32_fp8((int)q, 0);
  f32x2 hi = __builtin_amdgcn_cvt_pk_f32_fp8((int)q, 1);
  f[0] = lo.x; f[1] = lo.y; f[2] = hi.x; f[3] = hi.y;
#else
  f[0] = dec8_sw(q & 0xff); f[1] = dec8_sw((q >> 8) & 0xff);
  f[2] = dec8_sw((q >> 16) & 0xff); f[3] = dec8_sw(q >> 24);
#endif
}

// ---------------- merged prep: cvtx(+fp8) | cvtwBL | wa | hist ----------------
#define PB_CVTX 12500
#define PB_WBL  1280   // 4*64*1280/256
#define PB_WA   128
#define PB_HIST 3907
__global__ __launch_bounds__(256) void prep_k(const float* __restrict__ x,
                                              const float* __restrict__ W,
                                              const float* __restrict__ loop_w,
                                              const float* __restrict__ al,
                                              const float* __restrict__ ar,
                                              const int* __restrict__ edst,
                                              u16* __restrict__ xb,
                                              unsigned* __restrict__ xq,
                                              u16* __restrict__ WBL,
                                              u16* __restrict__ WAt,
                                              int* __restrict__ counts) {
  int bi = blockIdx.x;
  int tid = threadIdx.x;
  if (bi < PB_CVTX) {
    int i = bi * 256 + tid;  // group of 4 elements
    float4 v = ((const float4*)x)[i];
    uint2 o;
    o.x = (unsigned)f2b(v.x) | ((unsigned)f2b(v.y) << 16);
    o.y = (unsigned)f2b(v.z) | ((unsigned)f2b(v.w) << 16);
    ((uint2*)xb)[i] = o;
    xq[i] = enc4(v.x, v.y, v.z, v.w);
  } else if (bi < PB_CVTX + PB_WBL) {
    // WBL[h][n(64)][k'(1280)]: k'<1024 -> 0.25*W[k'>>8][k'&255][h*64+n]; else loop_w
    int g = (bi - PB_CVTX) * 256 + tid;
    int h = g / 81920, rem = g - h * 81920;
    int np = rem / 1280, kp = rem - np * 1280;
    float v;
    if (kp < 1024)
      v = 0.25f * W[(size_t)(kp >> 8) * 65536 + (size_t)(kp & 255) * 256 + h * 64 + np];
    else
      v = loop_w[(size_t)(kp - 1024) * 256 + h * 64 + np];
    WBL[g] = f2b(v);
  } else if (bi < PB_CVTX + PB_WBL + PB_WA) {
    int g = (bi - PB_CVTX - PB_WBL) * 256 + tid;
    int c = g >> 8, k = g & 255;
    float acc = 0.f;
    if (c < 32) {
      int cc = c & 15;
      int r = cc >> 2, h = cc & 3;
      const float* vec = ((c < 16) ? al : ar) + r * 256 + h * 64;
      const float* wrow = W + (size_t)r * 65536 + (size_t)k * 256 + h * 64;
      #pragma unroll 8
      for (int j = 0; j < 64; ++j) acc += wrow[j] * vec[j];
    }
    WAt[(size_t)c * 256 + k] = f2b(acc);
  } else {
    int g = (bi - PB_CVTX - PB_WBL - PB_WA) * 256 + tid;
    if (g < NREL * NEDGE) {
      int r = g / NEDGE;
      atomicAdd(&counts[r * NDST + edst[g]], 1);
    }
  }
}

// ---------------- elr GEMM: elr[NSRC][32] = xb @ WAt^T (N=32 tile) ----------------
// Block 256thr = 4 waves; M=128 (wave owns 32 rows x 32 cols), K=256.
__global__ __launch_bounds__(256) void gemmE_k(const u16* __restrict__ A,
                                               const u16* __restrict__ B,
                                               float* __restrict__ outF) {
  __shared__ u16 As[128 * 64];
  __shared__ u16 Bs[32 * 64];
  const int tid = threadIdx.x;
  const int w = tid >> 6, l = tid & 63;
  const int bm = blockIdx.y * 128;
  const int wm = w * 32;
  f32x4 acc[2][2] = {};
  const int lrow = l >> 3, lchunk = l & 7;

  for (int t = 0; t < 4; ++t) {
    const int k0 = t * 64;
    #pragma unroll
    for (int c = 0; c < 4; ++c) {
      int rb = (w * 4 + c) * 8;
      int row_in = rb + lrow;
      int colb = (lchunk * 16) ^ ((row_in & 7) << 4);
      long arow = bm + row_in;
      if (arow >= NSRC) arow = NSRC - 1;
      const char* ga = (const char*)A + ((size_t)arow * 256 + k0) * 2 + colb;
      GLD16(ga, (char*)As + rb * 128);
    }
    {
      int rb = w * 8;
      int row_in = rb + lrow;
      int colb = (lchunk * 16) ^ ((row_in & 7) << 4);
      const char* gb = (const char*)B + ((size_t)row_in * 256 + k0) * 2 + colb;
      GLD16(gb, (char*)Bs + rb * 128);
    }
    __syncthreads();
    #pragma unroll
    for (int kk = 0; kk < 2; ++kk) {
      bf16x8 af[2], bg[2];
      #pragma unroll
      for (int m = 0; m < 2; ++m) {
        int row = wm + m * 16 + (l & 15);
        int colb = (kk * 64 + ((l >> 4) * 16)) ^ ((row & 7) << 4);
        af[m] = *(const bf16x8*)((const char*)As + row * 128 + colb);
      }
      #pragma unroll
      for (int n = 0; n < 2; ++n) {
        int row = n * 16 + (l & 15);
        int colb = (kk * 64 + ((l >> 4) * 16)) ^ ((row & 7) << 4);
        bg[n] = *(const bf16x8*)((const char*)Bs + row * 128 + colb);
      }
      #pragma unroll
      for (int m = 0; m < 2; ++m)
        #pragma unroll
        for (int n = 0; n < 2; ++n)
          acc[m][n] = __builtin_amdgcn_mfma_f32_16x16x32_bf16(af[m], bg[n], acc[m][n], 0, 0, 0);
    }
    __syncthreads();
  }
  #pragma unroll
  for (int m = 0; m < 2; ++m) {
    #pragma unroll
    for (int j = 0; j < 4; ++j) {
      int row = bm + wm + m * 16 + (l >> 4) * 4 + j;
      if (row < NSRC) {
        #pragma unroll
        for (int n = 0; n < 2; ++n) {
          int col = n * 16 + (l & 15);
          outF[(size_t)row * 32 + col] = acc[m][n][j];
        }
      }
    }
  }
}

// ---------------- fused final GEMM, full-util N=64 tile (z = head) ----------------
// out[d][h*64+j] = relu( [xagg_h(1024) | xb(256)] @ WBL[h][j][.] + loop_b[h*64+j] )
// Block 256thr = 4 waves; tile M=128 (wave owns 32 rows), N=64, K=1280.
__global__ __launch_bounds__(256) void gemmF_k(const u16* __restrict__ xaggB,
                                               const u16* __restrict__ xb,
                                               const u16* __restrict__ WBL,
                                               const float* __restrict__ loop_b,
                                               float* __restrict__ out) {
  __shared__ u16 As[128 * 64];
  __shared__ u16 Bs[64 * 64];
  const int tid = threadIdx.x;
  const int w = tid >> 6, l = tid & 63;
  const int h = blockIdx.z;
  const int bm = blockIdx.y * 128;
  const int wm = w * 32;
  const u16* A1 = xaggB + (size_t)h * NDST * 1024;
  const u16* Bh = WBL + (size_t)h * 64 * 1280;
  f32x4 acc[2][4] = {};
  const int lrow = l >> 3, lchunk = l & 7;

  for (int t = 0; t < 20; ++t) {
    const int k0 = t * 64;
    #pragma unroll
    for (int c = 0; c < 4; ++c) {
      int rb = (w * 4 + c) * 8;
      int row_in = rb + lrow;
      int colb = (lchunk * 16) ^ ((row_in & 7) << 4);
      long arow = bm + row_in;
      if (arow >= NDST) arow = NDST - 1;
      const char* ga;
      if (k0 < 1024)
        ga = (const char*)A1 + ((size_t)arow * 1024 + k0) * 2 + colb;
      else
        ga = (const char*)xb + ((size_t)arow * 256 + (k0 - 1024)) * 2 + colb;
      GLD16(ga, (char*)As + rb * 128);
    }
    #pragma unroll
    for (int c = 0; c < 2; ++c) {
      int rb = (w * 2 + c) * 8;
      int row_in = rb + lrow;
      int colb = (lchunk * 16) ^ ((row_in & 7) << 4);
      const char* gb = (const char*)Bh + ((size_t)row_in * 1280 + k0) * 2 + colb;
      GLD16(gb, (char*)Bs + rb * 128);
    }
    __syncthreads();
    #pragma unroll
    for (int kk = 0; kk < 2; ++kk) {
      bf16x8 af[2], bg[4];
      #pragma unroll
      for (int m = 0; m < 2; ++m) {
        int row = wm + m * 16 + (l & 15);
        int colb = (kk * 64 + ((l >> 4) * 16)) ^ ((row & 7) << 4);
        af[m] = *(const bf16x8*)((const char*)As + row * 128 + colb);
      }
      #pragma unroll
      for (int n = 0; n < 4; ++n) {
        int row = n * 16 + (l & 15);
        int colb = (kk * 64 + ((l >> 4) * 16)) ^ ((row & 7) << 4);
        bg[n] = *(const bf16x8*)((const char*)Bs + row * 128 + colb);
      }
      #pragma unroll
      for (int m = 0; m < 2; ++m)
        #pragma unroll
        for (int n = 0; n < 4; ++n)
          acc[m][n] = __builtin_amdgcn_mfma_f32_16x16x32_bf16(af[m], bg[n], acc[m][n], 0, 0, 0);
    }
    __syncthreads();
  }
  #pragma unroll
  for (int m = 0; m < 2; ++m) {
    #pragma unroll
    for (int j = 0; j < 4; ++j) {
      int row = bm + wm + m * 16 + (l >> 4) * 4 + j;
      if (row < NDST) {
        #pragma unroll
        for (int n = 0; n < 4; ++n) {
          int col = n * 16 + (l & 15);
          out[(size_t)row * 256 + h * 64 + col] =
              fmaxf(acc[m][n][j] + loop_b[h * 64 + col], 0.f);
        }
      }
    }
  }
}

// ---------------- CSR scans / scatter ----------------
__global__ __launch_bounds__(1024) void scanA_k(const int* __restrict__ counts,
                                                int* __restrict__ offsets,
                                                int* __restrict__ btot) {
  __shared__ int wsum[16];
  int tid = threadIdx.x, lane = tid & 63, wid = tid >> 6;
  int i = blockIdx.x * 1024 + tid;
  int v = (i < NREL * NDST) ? counts[i] : 0;
  int x = v;
  #pragma unroll
  for (int off = 1; off < 64; off <<= 1) {
    int t = __shfl_up(x, off);
    if (lane >= off) x += t;
  }
  if (lane == 63) wsum[wid] = x;
  __syncthreads();
  if (wid == 0) {
    int t = (lane < 16) ? wsum[lane] : 0;
    #pragma unroll
    for (int off = 1; off < 16; off <<= 1) {
      int u = __shfl_up(t, off);
      if (lane >= off) t += u;
    }
    if (lane < 16) wsum[lane] = t;
  }
  __syncthreads();
  int wpre = (wid > 0) ? wsum[wid - 1] : 0;
  int incl = x + wpre;
  if (i < NREL * NDST) offsets[i] = incl - v;
  if (tid == 1023) btot[blockIdx.x] = incl;
}

__global__ void scanB_k(const int* __restrict__ btot, int* __restrict__ carry) {
  int lane = threadIdx.x;  // 64 threads = 1 wave
  int v = (lane < 40) ? btot[lane] : 0;
  int x = v;
  #pragma unroll
  for (int off = 1; off < 64; off <<= 1) {
    int t = __shfl_up(x, off);
    if (lane >= off) x += t;
  }
  if (lane < 40) carry[lane] = x - v;
}

__global__ __launch_bounds__(1024) void scanC_k(int* __restrict__ offsets,
                                                const int* __restrict__ carry,
                                                int* __restrict__ cursor) {
  int i = blockIdx.x * 1024 + threadIdx.x;
  if (i < NREL * NDST) {
    int o = offsets[i] + carry[blockIdx.x];
    offsets[i] = o;
    cursor[i] = o;
  }
  if (i == 0) offsets[NREL * NDST] = NREL * NEDGE;
}

__global__ void scatter_k(const int* __restrict__ esrc, const int* __restrict__ edst,
                          int* __restrict__ cursor, int* __restrict__ perm_src) {
  int g = blockIdx.x * 256 + threadIdx.x;
  if (g >= NREL * NEDGE) return;
  int r = g / NEDGE;
  int pos = atomicAdd(&cursor[r * NDST + edst[g]], 1);
  perm_src[pos] = esrc[g];
}

// ---------------- fused softmax + per-head x-aggregation (fp8 gather) ----------------
// Block = one dst, 4 waves; wave r owns segment (r,d). LDS alpha-cache; phase B
// gathers 256B fp8 x-rows, 8-edge unroll (8 outstanding gathers/lane);
// lane owns 4 ch x 4 head acc.
static __device__ __forceinline__ void edge_fma(float (&ac)[4][4], float4 a4, unsigned q) {
  float f[4];
  dec4(q, f);
  const float ah[4] = {a4.x, a4.y, a4.z, a4.w};
  #pragma unroll
  for (int h = 0; h < 4; ++h)
    #pragma unroll
    for (int c = 0; c < 4; ++c)
      ac[h][c] = fmaf(ah[h], f[c], ac[h][c]);
}

__global__ __launch_bounds__(256) void agg_k(const unsigned* __restrict__ xq,
                                             const int* __restrict__ offs,
                                             const int* __restrict__ perm,
                                             const float* __restrict__ elr,
                                             u16* __restrict__ xaggB) {
  __shared__ float sex[4][EMAXC][4];  // [wave][edge][head] normalized alpha
  const int d = blockIdx.x;
  const int r = threadIdx.x >> 6, lane = threadIdx.x & 63;
  const int seg = r * NDST + d;
  const int beg = offs[seg], end = offs[seg + 1];
  const int n = end - beg;
  const float4 r4 = *(const float4*)(elr + (size_t)d * 32 + 16 + r * 4);

  // phase A: denominators + exp cache
  float s0 = 0.f, s1 = 0.f, s2 = 0.f, s3 = 0.f;
  for (int e = lane; e < n; e += 64) {
    int s = perm[beg + e];
    float4 l4 = *(const float4*)(elr + (size_t)s * 32 + r * 4);
    float e0 = __expf(leaky(l4.x + r4.x));
    float e1 = __expf(leaky(l4.y + r4.y));
    float e2 = __expf(leaky(l4.z + r4.z));
    float e3 = __expf(leaky(l4.w + r4.w));
    if (e < EMAXC) *(float4*)&sex[r][e][0] = make_float4(e0, e1, e2, e3);
    s0 += e0; s1 += e1; s2 += e2; s3 += e3;
  }
  #pragma unroll
  for (int off = 1; off < 64; off <<= 1) {
    s0 += __shfl_xor(s0, off);
    s1 += __shfl_xor(s1, off);
    s2 += __shfl_xor(s2, off);
    s3 += __shfl_xor(s3, off);
  }
  const float rd0 = 1.f / fmaxf(s0, 1e-9f);
  const float rd1 = 1.f / fmaxf(s1, 1e-9f);
  const float rd2 = 1.f / fmaxf(s2, 1e-9f);
  const float rd3 = 1.f / fmaxf(s3, 1e-9f);
  for (int e = lane; e < n && e < EMAXC; e += 64) {
    float4 v = *(const float4*)&sex[r][e][0];
    *(float4*)&sex[r][e][0] = make_float4(v.x * rd0, v.y * rd1, v.z * rd2, v.w * rd3);
  }
  __syncthreads();

  // phase B: lane owns channels [lane*4, lane*4+4); 8-edge unroll
  float ac[4][4] = {};  // [head][ch]
  const int nc = (n < EMAXC) ? n : EMAXC;
  int e = 0;
  for (; e + 7 < nc; e += 8) {
    int sE[8];
    #pragma unroll
    for (int u = 0; u < 8; ++u) sE[u] = perm[beg + e + u];
    unsigned qE[8];
    #pragma unroll
    for (int u = 0; u < 8; ++u) qE[u] = xq[(size_t)sE[u] * 64 + lane];
    #pragma unroll
    for (int u = 0; u < 8; ++u) {
      float4 a4 = *(const float4*)&sex[r][e + u][0];
      edge_fma(ac, a4, qE[u]);
    }
  }
  for (; e < nc; ++e) {
    int s = perm[beg + e];
    float4 aa = *(const float4*)&sex[r][e][0];
    unsigned q = xq[(size_t)s * 64 + lane];
    edge_fma(ac, aa, q);
  }
  // overflow path (degree > EMAXC; essentially never for this graph)
  for (int i = EMAXC; i < n; ++i) {
    int s = perm[beg + i];
    float4 l4 = *(const float4*)(elr + (size_t)s * 32 + r * 4);
    float4 aa;
    aa.x = __expf(leaky(l4.x + r4.x)) * rd0;
    aa.y = __expf(leaky(l4.y + r4.y)) * rd1;
    aa.z = __expf(leaky(l4.z + r4.z)) * rd2;
    aa.w = __expf(leaky(l4.w + r4.w)) * rd3;
    unsigned q = xq[(size_t)s * 64 + lane];
    edge_fma(ac, aa, q);
  }

  // direct write: xaggB[h][d][r*256 + lane*4 ..]
  #pragma unroll
  for (int h = 0; h < 4; ++h) {
    uint2 o;
    o.x = (unsigned)f2b(ac[h][0]) | ((unsigned)f2b(ac[h][1]) << 16);
    o.y = (unsigned)f2b(ac[h][2]) | ((unsigned)f2b(ac[h][3]) << 16);
    *(uint2*)(xaggB + ((size_t)h * NDST + d) * 1024 + (size_t)r * 256 + (size_t)lane * 4) = o;
  }
}

// ---------------- launcher ----------------
extern "C" void kernel_launch(void* const* d_in, const int* in_sizes, int n_in,
                              void* d_out, int out_size, void* d_ws, size_t ws_size,
                              hipStream_t stream) {
  const float* x      = (const float*)d_in[0];
  const float* W      = (const float*)d_in[1];
  const float* attn_l = (const float*)d_in[2];
  const float* attn_r = (const float*)d_in[3];
  const float* loop_w = (const float*)d_in[4];
  const float* loop_b = (const float*)d_in[5];
  const int* edge_src = (const int*)d_in[6];
  const int* edge_dst = (const int*)d_in[7];
  float* out = (float*)d_out;

  char* wsp = (char*)d_ws;
  size_t off = 0;
  auto alloc = [&](size_t bytes) -> char* {
    char* p = wsp + off;
    off = (off + bytes + 255) & ~(size_t)255;
    return p;
  };
  u16* xb      = (u16*)alloc((size_t)NSRC * 256 * 2);        // 25.6 MB
  unsigned* xq = (unsigned*)alloc((size_t)NSRC * 64 * 4);    // 12.8 MB (fp8)
  u16* WBL     = (u16*)alloc((size_t)4 * 64 * 1280 * 2);     // 0.66 MB
  u16* WAt     = (u16*)alloc((size_t)128 * 256 * 2);         // 65 KB
  float* elr   = (float*)alloc((size_t)NSRC * 32 * 4);       // 6.4 MB
  u16* xaggB   = (u16*)alloc((size_t)4 * NDST * 1024 * 2);   // 81.9 MB
  int* counts  = (int*)alloc((size_t)NREL * NDST * 4);
  int* offs    = (int*)alloc((size_t)(NREL * NDST + 1) * 4);
  int* cursor  = (int*)alloc((size_t)NREL * NDST * 4);
  int* btot    = (int*)alloc(64 * 4);
  int* carry   = (int*)alloc(64 * 4);
  int* perm    = (int*)alloc((size_t)NREL * NEDGE * 4);      // total ~136 MB

  hipMemsetAsync(counts, 0, (size_t)NREL * NDST * 4, stream);

  // merged prep: cvtx(+fp8) | WBL | WAt | hist
  prep_k<<<PB_CVTX + PB_WBL + PB_WA + PB_HIST, 256, 0, stream>>>(
      x, W, loop_w, attn_l, attn_r, edge_dst, xb, xq, WBL, WAt, counts);

  scanA_k<<<40, 1024, 0, stream>>>(counts, offs, btot);
  scanB_k<<<1, 64, 0, stream>>>(btot, carry);
  scanC_k<<<40, 1024, 0, stream>>>(offs, carry, cursor);
  scatter_k<<<(NREL * NEDGE + 255) / 256, 256, 0, stream>>>(
      edge_src, edge_dst, cursor, perm);

  // elr skinny GEMM: elr[NSRC][32] f32 (N=32 tile)
  gemmE_k<<<dim3(1, (NSRC + 127) / 128), 256, 0, stream>>>(xb, WAt, elr);

  // fused softmax + per-head x-aggregation (fp8 gather) -> xaggB
  agg_k<<<NDST, 256, 0, stream>>>(xq, offs, perm, elr, xaggB);

  // fused final: out = relu([xagg_h | xb] @ WBL_h^T + loop_b), z = head
  gemmF_k<<<dim3(1, (NDST + 127) / 128, 4), 256, 0, stream>>>(
      xaggB, xb, WBL, loop_b, out);
}